// Round 1
// baseline (262.700 us; speedup 1.0000x reference)
//
#include <hip/hip_runtime.h>

#define NROWS 8192
#define DDIM  256
#define KSPLIT 4
#define BM 64
#define BK 64
#define NTILES (NROWS / KSPLIT / BK)   // 32

typedef __bf16 bf16x8 __attribute__((ext_vector_type(8)));
typedef float  f32x4  __attribute__((ext_vector_type(4)));

typedef __attribute__((address_space(1))) unsigned int uint_gas;
typedef __attribute__((address_space(3))) unsigned int uint_las;

__device__ __forceinline__ void gload_lds16(const void* g, void* l) {
  __builtin_amdgcn_global_load_lds((const uint_gas*)g, (uint_las*)l, 16, 0, 0);
}

__device__ __forceinline__ unsigned int f2bf_bits(float f) {
  union { float f; unsigned int u; } v; v.f = f;
  unsigned int r = v.u + 0x7FFFu + ((v.u >> 16) & 1u);
  return r >> 16;
}
__device__ __forceinline__ float bf2f(unsigned int b) {
  union { unsigned int u; float f; } v; v.u = b << 16;
  return v.f;
}

// ---------------- kernel 0: fp32 -> bf16 conversion ----------------
__global__ __launch_bounds__(256) void convert_kernel(
    const float* __restrict__ x, const float* __restrict__ wq,
    const float* __restrict__ wk, const float* __restrict__ wv,
    unsigned short* __restrict__ xb, unsigned short* __restrict__ Wb)
{
  int i = blockIdx.x * 256 + threadIdx.x;
  const int nx4 = NROWS * DDIM / 4;
  const int nw4 = DDIM * DDIM / 4;
  const float4* src; unsigned short* dst; int j;
  if (i < nx4)              { src = (const float4*)x;  dst = xb;                j = i; }
  else if (i < nx4 +   nw4) { src = (const float4*)wq; dst = Wb;                j = i - nx4; }
  else if (i < nx4 + 2*nw4) { src = (const float4*)wk; dst = Wb + DDIM*DDIM;    j = i - nx4 - nw4; }
  else                      { src = (const float4*)wv; dst = Wb + 2*DDIM*DDIM;  j = i - nx4 - 2*nw4; }
  float4 f = src[j];
  ushort4 o;
  o.x = (unsigned short)f2bf_bits(f.x);
  o.y = (unsigned short)f2bf_bits(f.y);
  o.z = (unsigned short)f2bf_bits(f.z);
  o.w = (unsigned short)f2bf_bits(f.w);
  ((ushort4*)dst)[j] = o;
}

// ---------------- kernel 1: QKV projections + L2 norm + vT ----------------
__global__ __launch_bounds__(256) void qkv_kernel(
    const float* __restrict__ bq, const float* __restrict__ bk, const float* __restrict__ bv,
    const unsigned short* __restrict__ xb, const unsigned short* __restrict__ Wb,
    unsigned short* __restrict__ qb, unsigned short* __restrict__ kb,
    unsigned short* __restrict__ vb, unsigned short* __restrict__ vT)
{
  __shared__ unsigned short vstage[DDIM * 72];   // transposed v staging, padded
  const int t = threadIdx.x;
  const int w = t >> 6, l = t & 63;
  const int c = l & 15, g = l >> 4;
  const int row0 = blockIdx.x * BM;
  const int rw = row0 + w * 16;

  bf16x8 a[8];
  #pragma unroll
  for (int ks = 0; ks < 8; ks++)
    a[ks] = *(const bf16x8*)(xb + (size_t)(rw + c) * DDIM + ks * 32 + g * 8);

  #pragma unroll
  for (int out = 0; out < 3; out++) {
    const unsigned short* W = Wb + out * DDIM * DDIM;
    const float* bias = (out == 0) ? bq : (out == 1) ? bk : bv;
    unsigned short* dst = (out == 0) ? qb : (out == 1) ? kb : vb;
    f32x4 vals[16];
    #pragma unroll
    for (int ct = 0; ct < 16; ct++) {
      f32x4 acc = {0.f, 0.f, 0.f, 0.f};
      #pragma unroll
      for (int ks = 0; ks < 8; ks++) {
        bf16x8 b = *(const bf16x8*)(W + (size_t)(ct * 16 + c) * DDIM + ks * 32 + g * 8);
        acc = __builtin_amdgcn_mfma_f32_16x16x32_bf16(a[ks], b, acc, 0, 0, 0);
      }
      float bias_v = bias[ct * 16 + c];
      #pragma unroll
      for (int r = 0; r < 4; r++) acc[r] += bias_v;
      vals[ct] = acc;
    }
    if (out < 2) {   // L2 normalize rows (q, k)
      #pragma unroll
      for (int r = 0; r < 4; r++) {
        float ss = 0.f;
        #pragma unroll
        for (int ct = 0; ct < 16; ct++) ss += vals[ct][r] * vals[ct][r];
        ss += __shfl_xor(ss, 1); ss += __shfl_xor(ss, 2);
        ss += __shfl_xor(ss, 4); ss += __shfl_xor(ss, 8);
        float inv = 1.f / fmaxf(sqrtf(ss), 1e-12f);
        #pragma unroll
        for (int ct = 0; ct < 16; ct++) vals[ct][r] *= inv;
      }
    }
    #pragma unroll
    for (int ct = 0; ct < 16; ct++) {
      #pragma unroll
      for (int r = 0; r < 4; r++) {
        unsigned int bits = f2bf_bits(vals[ct][r]);
        unsigned int ob = (unsigned int)__shfl_xor((int)bits, 1);
        if (!(l & 1))
          *(unsigned int*)(dst + (size_t)(rw + g * 4 + r) * DDIM + ct * 16 + c) =
              bits | (ob << 16);
        if (out == 2)
          vstage[(ct * 16 + c) * 72 + (w * 16 + g * 4 + r)] = (unsigned short)bits;
      }
    }
  }
  __syncthreads();
  // store vT tile: vT[d][row0..row0+64)
  #pragma unroll
  for (int p = 0; p < 8; p++) {
    int dd = (t >> 3) + p * 32;
    int ch = t & 7;
    *(uint4*)(vT + (size_t)dd * NROWS + row0 + ch * 8) =
        *(const uint4*)(vstage + dd * 72 + ch * 8);
  }
}

// ---------------- kernel 2: fused relu-attention partials ----------------
__global__ __launch_bounds__(256) void attn_kernel(
    const unsigned short* __restrict__ qb, const unsigned short* __restrict__ kb,
    const unsigned short* __restrict__ vT,
    float* __restrict__ nump, float* __restrict__ denp)
{
  __shared__ unsigned short k_lds[BK * DDIM];    // 32 KB, XOR-swizzled slots
  __shared__ unsigned short vt_lds[DDIM * BK];   // 32 KB, XOR-swizzled slots
  __shared__ unsigned short P[BM * 72];          // 9 KB, padded stride 72

  const int t = threadIdx.x;
  const int w = t >> 6, l = t & 63;
  const int c = l & 15, g = l >> 4;
  const int wr = w >> 1, wc = w & 1;
  const int bid = blockIdx.x;
  const int split = bid & (KSPLIT - 1);
  const int mb = bid >> 2;
  const int q0 = mb * BM;
  const int kbase0 = split * (NROWS / KSPLIT);

  // hoist q fragments into registers: 2 row-tiles x 8 k-steps
  bf16x8 qa[2][8];
  #pragma unroll
  for (int rt = 0; rt < 2; rt++)
    #pragma unroll
    for (int ks = 0; ks < 8; ks++)
      qa[rt][ks] = *(const bf16x8*)(qb + (size_t)(q0 + wr*32 + rt*16 + c) * DDIM + ks*32 + g*8);

  f32x4 oacc[2][8];
  #pragma unroll
  for (int rt = 0; rt < 2; rt++)
    #pragma unroll
    for (int dt = 0; dt < 8; dt++)
      oacc[rt][dt] = (f32x4){0.f, 0.f, 0.f, 0.f};
  float den[2][4] = {{0.f,0.f,0.f,0.f},{0.f,0.f,0.f,0.f}};

  const char* kbc = (const char*)kb;
  const char* vtc = (const char*)vT;

  for (int it = 0; it < NTILES; it++) {
    const int kbase = kbase0 + it * BK;
    // stage K tile (64x256 bf16): linear LDS dest, swizzled global source
    #pragma unroll
    for (int i = 0; i < 8; i++) {
      int n = i * 256 + t;
      int row = n >> 5, slot = n & 31;
      gload_lds16(kbc + (size_t)(kbase + row) * 512 + ((slot ^ (row & 7)) * 16),
                  (char*)k_lds + i * 4096 + w * 1024);
    }
    // stage vT tile (256 x 64 bf16)
    #pragma unroll
    for (int i = 0; i < 8; i++) {
      int n = i * 256 + t;
      int dd = n >> 3, slot = n & 7;
      gload_lds16(vtc + (size_t)dd * (NROWS*2) + (size_t)kbase * 2 + ((slot ^ (dd & 7)) * 16),
                  (char*)vt_lds + i * 4096 + w * 1024);
    }
    __syncthreads();

    // S = q . k^T for this wave's 32 rows x 32 cols
    f32x4 sacc[2][2];
    #pragma unroll
    for (int rt = 0; rt < 2; rt++)
      #pragma unroll
      for (int kt = 0; kt < 2; kt++)
        sacc[rt][kt] = (f32x4){0.f, 0.f, 0.f, 0.f};
    #pragma unroll
    for (int ks = 0; ks < 8; ks++) {
      bf16x8 kf[2];
      #pragma unroll
      for (int kt = 0; kt < 2; kt++) {
        int rl = wc * 32 + kt * 16 + c;
        kf[kt] = *(const bf16x8*)((const char*)k_lds + rl * 512 +
                                  ((ks * 64 + g * 16) ^ ((rl & 7) << 4)));
      }
      #pragma unroll
      for (int rt = 0; rt < 2; rt++)
        #pragma unroll
        for (int kt = 0; kt < 2; kt++)
          sacc[rt][kt] = __builtin_amdgcn_mfma_f32_16x16x32_bf16(qa[rt][ks], kf[kt],
                                                                 sacc[rt][kt], 0, 0, 0);
    }
    // relu, denominator accumulate, pack P to LDS (pairs via shfl)
    #pragma unroll
    for (int rt = 0; rt < 2; rt++)
      #pragma unroll
      for (int kt = 0; kt < 2; kt++)
        #pragma unroll
        for (int r = 0; r < 4; r++) {
          float v = fmaxf(sacc[rt][kt][r], 0.f);
          den[rt][r] += v;
          unsigned int bits = f2bf_bits(v);
          unsigned int ob = (unsigned int)__shfl_xor((int)bits, 1);
          if (!(l & 1)) {
            int prow = wr * 32 + rt * 16 + g * 4 + r;
            int pcol = wc * 32 + kt * 16 + c;   // even
            *(unsigned int*)(P + prow * 72 + pcol) = bits | (ob << 16);
          }
        }
    __syncthreads();

    // PV: this wave's 32 rows x 128 d-cols
    #pragma unroll
    for (int ks2 = 0; ks2 < 2; ks2++) {
      bf16x8 pa[2];
      #pragma unroll
      for (int rt = 0; rt < 2; rt++)
        pa[rt] = *(const bf16x8*)((const char*)P + (wr*32 + rt*16 + c) * 144 +
                                  (ks2*32 + g*8) * 2);
      bf16x8 vf[8];
      #pragma unroll
      for (int dt = 0; dt < 8; dt++) {
        int dl = wc * 128 + dt * 16 + c;
        vf[dt] = *(const bf16x8*)((const char*)vt_lds + dl * 128 +
                                  ((ks2 * 64 + g * 16) ^ ((dl & 7) << 4)));
      }
      #pragma unroll
      for (int rt = 0; rt < 2; rt++)
        #pragma unroll
        for (int dt = 0; dt < 8; dt++)
          oacc[rt][dt] = __builtin_amdgcn_mfma_f32_16x16x32_bf16(pa[rt], vf[dt],
                                                                 oacc[rt][dt], 0, 0, 0);
    }
    __syncthreads();
  }

  // write numerator partials
  float* np = nump + (size_t)split * NROWS * DDIM;
  #pragma unroll
  for (int rt = 0; rt < 2; rt++)
    #pragma unroll
    for (int dt = 0; dt < 8; dt++)
      #pragma unroll
      for (int r = 0; r < 4; r++) {
        int rowg = q0 + wr*32 + rt*16 + g*4 + r;
        int col  = wc*128 + dt*16 + c;
        np[(size_t)rowg * DDIM + col] = oacc[rt][dt][r];
      }
  // reduce + write denominator partials
  #pragma unroll
  for (int rt = 0; rt < 2; rt++)
    #pragma unroll
    for (int r = 0; r < 4; r++) {
      float d = den[rt][r];
      d += __shfl_xor(d, 1); d += __shfl_xor(d, 2);
      d += __shfl_xor(d, 4); d += __shfl_xor(d, 8);
      if (c == 0)
        denp[((size_t)split * 2 + wc) * NROWS + q0 + wr*32 + rt*16 + g*4 + r] = d;
    }
}

// ---------------- kernel 3: combine partials, diagonal fix, output ----------------
__global__ __launch_bounds__(256) void combine_kernel(
    const float* __restrict__ x, const unsigned short* __restrict__ qb,
    const unsigned short* __restrict__ kb, const unsigned short* __restrict__ vb,
    const float* __restrict__ nump, const float* __restrict__ denp,
    float* __restrict__ out)
{
  const int t = threadIdx.x;
  const int w = t >> 6, l = t & 63;
  const int i = blockIdx.x * 4 + w;

  ushort4 q4 = *(const ushort4*)(qb + (size_t)i * DDIM + l * 4);
  ushort4 k4 = *(const ushort4*)(kb + (size_t)i * DDIM + l * 4);
  float s = bf2f(q4.x) * bf2f(k4.x) + bf2f(q4.y) * bf2f(k4.y)
          + bf2f(q4.z) * bf2f(k4.z) + bf2f(q4.w) * bf2f(k4.w);
  #pragma unroll
  for (int m = 1; m < 64; m <<= 1) s += __shfl_xor(s, m);
  float r  = fmaxf(s, 0.f);
  float rb = bf2f(f2bf_bits(r));   // match phase-2's bf16-rounded P value

  float den = 0.f;
  #pragma unroll
  for (int sp = 0; sp < KSPLIT; sp++)
    den += denp[(size_t)(sp * 2) * NROWS + i] + denp[(size_t)(sp * 2 + 1) * NROWS + i];
  float inv = 1.f / fmaxf(den - r, 1e-12f);

  const int d0 = l * 4;
  float4 acc = *(const float4*)(nump + (size_t)i * DDIM + d0);
  #pragma unroll
  for (int sp = 1; sp < KSPLIT; sp++) {
    float4 a2 = *(const float4*)(nump + (size_t)sp * NROWS * DDIM + (size_t)i * DDIM + d0);
    acc.x += a2.x; acc.y += a2.y; acc.z += a2.z; acc.w += a2.w;
  }
  ushort4 v4 = *(const ushort4*)(vb + (size_t)i * DDIM + d0);
  float4 xx = *(const float4*)(x + (size_t)i * DDIM + d0);
  float4 o;
  o.x = (acc.x - rb * bf2f(v4.x)) * inv + xx.x;
  o.y = (acc.y - rb * bf2f(v4.y)) * inv + xx.y;
  o.z = (acc.z - rb * bf2f(v4.z)) * inv + xx.z;
  o.w = (acc.w - rb * bf2f(v4.w)) * inv + xx.w;
  *(float4*)(out + (size_t)i * DDIM + d0) = o;
}

extern "C" void kernel_launch(void* const* d_in, const int* in_sizes, int n_in,
                              void* d_out, int out_size, void* d_ws, size_t ws_size,
                              hipStream_t stream)
{
  const float* x  = (const float*)d_in[0];
  const float* Wq = (const float*)d_in[1];
  const float* bq = (const float*)d_in[2];
  const float* Wk = (const float*)d_in[3];
  const float* bk = (const float*)d_in[4];
  const float* Wv = (const float*)d_in[5];
  const float* bv = (const float*)d_in[6];

  char* ws = (char*)d_ws;
  unsigned short* xb  = (unsigned short*)(ws + 0);          // 4 MB
  unsigned short* Wb  = (unsigned short*)(ws + 4194304);    // 384 KB (3 matrices)
  unsigned short* qb  = (unsigned short*)(ws + 4587520);    // 4 MB
  unsigned short* kb  = (unsigned short*)(ws + 8781824);    // 4 MB
  unsigned short* vb  = (unsigned short*)(ws + 12976128);   // 4 MB
  unsigned short* vT  = (unsigned short*)(ws + 17170432);   // 4 MB
  float* nump = (float*)(ws + 21364736);                    // 32 MB (4 splits)
  float* denp = (float*)(ws + 54919168);                    // 256 KB

  convert_kernel<<<2240, 256, 0, stream>>>(x, Wq, Wk, Wv, xb, Wb);
  qkv_kernel<<<NROWS / BM, 256, 0, stream>>>(bq, bk, bv, xb, Wb, qb, kb, vb, vT);
  attn_kernel<<<(NROWS / BM) * KSPLIT, 256, 0, stream>>>(qb, kb, vT, nump, denp);
  combine_kernel<<<NROWS / 4, 256, 0, stream>>>(x, qb, kb, vb, nump, denp, (float*)d_out);
}

// Round 2
// 157.462 us; speedup vs baseline: 1.6683x; 1.6683x over previous
//
#include <hip/hip_runtime.h>

#define NROWS 8192
#define DDIM  256
#define KSPLIT 4
#define BM 128
#define BK 64
#define NT (NROWS / KSPLIT / BK)   // 32 tiles per split

typedef __bf16 bf16x8 __attribute__((ext_vector_type(8)));
typedef float  f32x4  __attribute__((ext_vector_type(4)));

typedef __attribute__((address_space(1))) unsigned int uint_gas;
typedef __attribute__((address_space(3))) unsigned int uint_las;

__device__ __forceinline__ void gload_lds16(const void* g, void* l) {
  __builtin_amdgcn_global_load_lds((const uint_gas*)g, (uint_las*)l, 16, 0, 0);
}

__device__ __forceinline__ unsigned int f2bf_bits(float f) {
  union { float f; unsigned int u; } v; v.f = f;
  unsigned int r = v.u + 0x7FFFu + ((v.u >> 16) & 1u);
  return r >> 16;
}
__device__ __forceinline__ float bf2f(unsigned int b) {
  union { unsigned int u; float f; } v; v.u = b << 16;
  return v.f;
}

// ---------------- kernel 0: fp32 -> bf16 conversion ----------------
__global__ __launch_bounds__(256) void convert_kernel(
    const float* __restrict__ x, const float* __restrict__ wq,
    const float* __restrict__ wk, const float* __restrict__ wv,
    unsigned short* __restrict__ xb, unsigned short* __restrict__ Wb)
{
  int i = blockIdx.x * 256 + threadIdx.x;
  const int nx4 = NROWS * DDIM / 4;
  const int nw4 = DDIM * DDIM / 4;
  const float4* src; unsigned short* dst; int j;
  if (i < nx4)              { src = (const float4*)x;  dst = xb;                j = i; }
  else if (i < nx4 +   nw4) { src = (const float4*)wq; dst = Wb;                j = i - nx4; }
  else if (i < nx4 + 2*nw4) { src = (const float4*)wk; dst = Wb + DDIM*DDIM;    j = i - nx4 - nw4; }
  else                      { src = (const float4*)wv; dst = Wb + 2*DDIM*DDIM;  j = i - nx4 - 2*nw4; }
  float4 f = src[j];
  ushort4 o;
  o.x = (unsigned short)f2bf_bits(f.x);
  o.y = (unsigned short)f2bf_bits(f.y);
  o.z = (unsigned short)f2bf_bits(f.z);
  o.w = (unsigned short)f2bf_bits(f.w);
  ((ushort4*)dst)[j] = o;
}

// ---------------- kernel 1: QKV projections + L2 norm + vT ----------------
// grid = 384: out = bid/128 (0=q,1=k,2=v), mb = bid%128 (64-row slab)
__global__ __launch_bounds__(256) void qkv_kernel(
    const float* __restrict__ bq, const float* __restrict__ bk, const float* __restrict__ bv,
    const unsigned short* __restrict__ xb, const unsigned short* __restrict__ Wb,
    unsigned short* __restrict__ qb, unsigned short* __restrict__ kb,
    unsigned short* __restrict__ vb, unsigned short* __restrict__ vT)
{
  __shared__ unsigned short vstage[DDIM * 72];
  const int t = threadIdx.x;
  const int w = t >> 6, l = t & 63;
  const int c = l & 15, g = l >> 4;
  const int out = blockIdx.x / 128;
  const int mb  = blockIdx.x % 128;
  const int row0 = mb * 64;
  const int rw = row0 + w * 16;

  bf16x8 a[8];
  #pragma unroll
  for (int ks = 0; ks < 8; ks++)
    a[ks] = *(const bf16x8*)(xb + (size_t)(rw + c) * DDIM + ks * 32 + g * 8);

  const unsigned short* W = Wb + out * DDIM * DDIM;
  const float* bias = (out == 0) ? bq : (out == 1) ? bk : bv;
  unsigned short* dst = (out == 0) ? qb : (out == 1) ? kb : vb;
  f32x4 vals[16];
  #pragma unroll
  for (int ct = 0; ct < 16; ct++) {
    f32x4 acc = {0.f, 0.f, 0.f, 0.f};
    #pragma unroll
    for (int ks = 0; ks < 8; ks++) {
      bf16x8 b = *(const bf16x8*)(W + (size_t)(ct * 16 + c) * DDIM + ks * 32 + g * 8);
      acc = __builtin_amdgcn_mfma_f32_16x16x32_bf16(a[ks], b, acc, 0, 0, 0);
    }
    float bias_v = bias[ct * 16 + c];
    #pragma unroll
    for (int r = 0; r < 4; r++) acc[r] += bias_v;
    vals[ct] = acc;
  }
  if (out < 2) {   // L2 normalize rows (q, k)
    #pragma unroll
    for (int r = 0; r < 4; r++) {
      float ss = 0.f;
      #pragma unroll
      for (int ct = 0; ct < 16; ct++) ss += vals[ct][r] * vals[ct][r];
      ss += __shfl_xor(ss, 1); ss += __shfl_xor(ss, 2);
      ss += __shfl_xor(ss, 4); ss += __shfl_xor(ss, 8);
      float inv = 1.f / fmaxf(sqrtf(ss), 1e-12f);
      #pragma unroll
      for (int ct = 0; ct < 16; ct++) vals[ct][r] *= inv;
    }
  }
  #pragma unroll
  for (int ct = 0; ct < 16; ct++) {
    #pragma unroll
    for (int r = 0; r < 4; r++) {
      unsigned int bits = f2bf_bits(vals[ct][r]);
      unsigned int ob = (unsigned int)__shfl_xor((int)bits, 1);
      if (!(l & 1))
        *(unsigned int*)(dst + (size_t)(rw + g * 4 + r) * DDIM + ct * 16 + c) =
            bits | (ob << 16);
      if (out == 2)
        vstage[(ct * 16 + c) * 72 + (w * 16 + g * 4 + r)] = (unsigned short)bits;
    }
  }
  if (out == 2) {
    __syncthreads();
    #pragma unroll
    for (int p = 0; p < 8; p++) {
      int dd = (t >> 3) + p * 32;
      int ch = t & 7;
      *(uint4*)(vT + (size_t)dd * NROWS + row0 + ch * 8) =
          *(const uint4*)(vstage + dd * 72 + ch * 8);
    }
  }
}

// ---------------- kernel 2: fused relu-attention partials ----------------
// BM=128 q-rows/block, 8 waves (4 row x 2 col), double-buffered K/vT staging.
__global__ __launch_bounds__(512, 2) void attn_kernel(
    const unsigned short* __restrict__ qb, const unsigned short* __restrict__ kb,
    const unsigned short* __restrict__ vT,
    float* __restrict__ nump, float* __restrict__ denp)
{
  // 2x32KB K dbuf | 2x32KB vT dbuf | 18KB P (stride 72 ushort)
  __shared__ __align__(16) char smem[149504];
  char* kbuf = smem;
  char* vbuf = smem + 65536;
  unsigned short* P = (unsigned short*)(smem + 131072);

  const int t = threadIdx.x;
  const int w = t >> 6, l = t & 63;
  const int c = l & 15, g = l >> 4;
  const int wr = w >> 1, wc = w & 1;   // wr 0..3 (32 rows each), wc 0..1
  const int bid = blockIdx.x;
  const int split = bid & (KSPLIT - 1);
  const int mb = bid >> 2;
  const int q0 = mb * BM;
  const int kbase0 = split * (NROWS / KSPLIT);

  const char* kbc = (const char*)kb;
  const char* vtc = (const char*)vT;

  // hoist q fragments: 2 row-tiles x 8 k-steps = 64 VGPR
  bf16x8 qa[2][8];
  #pragma unroll
  for (int rt = 0; rt < 2; rt++)
    #pragma unroll
    for (int ks = 0; ks < 8; ks++)
      qa[rt][ks] = *(const bf16x8*)(qb + (size_t)(q0 + wr*32 + rt*16 + c) * DDIM + ks*32 + g*8);

  f32x4 oacc[2][8];
  #pragma unroll
  for (int rt = 0; rt < 2; rt++)
    #pragma unroll
    for (int dt = 0; dt < 8; dt++)
      oacc[rt][dt] = (f32x4){0.f, 0.f, 0.f, 0.f};
  float den[2][4] = {{0.f,0.f,0.f,0.f},{0.f,0.f,0.f,0.f}};

  auto stage = [&](int buf, int it) {
    const int kbase = kbase0 + it * BK;
    const char* ksrc = kbc + (size_t)kbase * 512;
    #pragma unroll
    for (int i = 0; i < 4; i++) {
      int n = i * 512 + t;
      int row = n >> 5, slot = n & 31;
      gload_lds16(ksrc + row * 512 + ((slot ^ (row & 7)) * 16),
                  kbuf + buf * 32768 + i * 8192 + w * 1024);
    }
    const char* vsrc = vtc + (size_t)kbase * 2;
    #pragma unroll
    for (int i = 0; i < 4; i++) {
      int n = i * 512 + t;
      int dd = n >> 3, slot = n & 7;
      gload_lds16(vsrc + (size_t)dd * (NROWS * 2) + ((slot ^ (dd & 7)) * 16),
                  vbuf + buf * 32768 + i * 8192 + w * 1024);
    }
  };

  // prologue: stage tile 0 into buf 0
  stage(0, 0);
  asm volatile("s_waitcnt vmcnt(0)" ::: "memory");
  __builtin_amdgcn_sched_barrier(0);
  __builtin_amdgcn_s_barrier();
  __builtin_amdgcn_sched_barrier(0);

  for (int it = 0; it < NT; ++it) {
    const int cur = it & 1;
    // issue next-tile prefetch (stays in flight across the mid barrier)
    if (it + 1 < NT) stage(cur ^ 1, it + 1);
    __builtin_amdgcn_sched_barrier(0);

    // ---- QK^T: this wave's 32 rows x 32 cols ----
    const char* kcur = kbuf + cur * 32768;
    f32x4 sacc[2][2];
    #pragma unroll
    for (int rt = 0; rt < 2; rt++)
      #pragma unroll
      for (int kt = 0; kt < 2; kt++)
        sacc[rt][kt] = (f32x4){0.f, 0.f, 0.f, 0.f};
    #pragma unroll
    for (int ks = 0; ks < 8; ks++) {
      bf16x8 kf[2];
      #pragma unroll
      for (int kt = 0; kt < 2; kt++) {
        int rl = wc * 32 + kt * 16 + c;
        kf[kt] = *(const bf16x8*)(kcur + rl * 512 + ((ks * 64 + g * 16) ^ ((rl & 7) << 4)));
      }
      #pragma unroll
      for (int rt = 0; rt < 2; rt++)
        #pragma unroll
        for (int kt = 0; kt < 2; kt++)
          sacc[rt][kt] = __builtin_amdgcn_mfma_f32_16x16x32_bf16(qa[rt][ks], kf[kt],
                                                                 sacc[rt][kt], 0, 0, 0);
    }
    // relu, denominator accumulate, pack P to LDS
    #pragma unroll
    for (int rt = 0; rt < 2; rt++)
      #pragma unroll
      for (int kt = 0; kt < 2; kt++)
        #pragma unroll
        for (int r = 0; r < 4; r++) {
          float v = fmaxf(sacc[rt][kt][r], 0.f);
          den[rt][r] += v;
          unsigned int bits = f2bf_bits(v);
          unsigned int ob = (unsigned int)__shfl_xor((int)bits, 1);
          if (!(l & 1)) {
            int prow = wr * 32 + rt * 16 + g * 4 + r;
            int pcol = wc * 32 + kt * 16 + c;   // even
            *(unsigned int*)(P + prow * 72 + pcol) = bits | (ob << 16);
          }
        }
    // P visibility barrier — LDS-only drain, prefetch loads stay in flight
    asm volatile("s_waitcnt lgkmcnt(0)" ::: "memory");
    __builtin_amdgcn_sched_barrier(0);
    __builtin_amdgcn_s_barrier();
    __builtin_amdgcn_sched_barrier(0);

    // ---- PV: this wave's 32 rows x 128 d-cols ----
    const char* vcur = vbuf + cur * 32768;
    #pragma unroll
    for (int ks2 = 0; ks2 < 2; ks2++) {
      bf16x8 pa[2];
      #pragma unroll
      for (int rt = 0; rt < 2; rt++)
        pa[rt] = *(const bf16x8*)((const char*)P + (wr*32 + rt*16 + c) * 144 +
                                  (ks2*32 + g*8) * 2);
      bf16x8 vf[8];
      #pragma unroll
      for (int dt = 0; dt < 8; dt++) {
        int dl = wc * 128 + dt * 16 + c;
        vf[dt] = *(const bf16x8*)(vcur + dl * 128 + ((ks2 * 64 + g * 16) ^ ((dl & 7) << 4)));
      }
      #pragma unroll
      for (int rt = 0; rt < 2; rt++)
        #pragma unroll
        for (int dt = 0; dt < 8; dt++)
          oacc[rt][dt] = __builtin_amdgcn_mfma_f32_16x16x32_bf16(pa[rt], vf[dt],
                                                                 oacc[rt][dt], 0, 0, 0);
    }
    // end-of-tile: next buffers staged (single counted drain point per iter)
    asm volatile("s_waitcnt vmcnt(0)" ::: "memory");
    __builtin_amdgcn_sched_barrier(0);
    __builtin_amdgcn_s_barrier();
    __builtin_amdgcn_sched_barrier(0);
  }

  // write numerator partials
  float* np = nump + (size_t)split * NROWS * DDIM;
  #pragma unroll
  for (int rt = 0; rt < 2; rt++)
    #pragma unroll
    for (int dt = 0; dt < 8; dt++)
      #pragma unroll
      for (int r = 0; r < 4; r++) {
        int rowg = q0 + wr*32 + rt*16 + g*4 + r;
        int col  = wc*128 + dt*16 + c;
        np[(size_t)rowg * DDIM + col] = oacc[rt][dt][r];
      }
  // reduce + write denominator partials
  #pragma unroll
  for (int rt = 0; rt < 2; rt++)
    #pragma unroll
    for (int r = 0; r < 4; r++) {
      float d = den[rt][r];
      d += __shfl_xor(d, 1); d += __shfl_xor(d, 2);
      d += __shfl_xor(d, 4); d += __shfl_xor(d, 8);
      if (c == 0)
        denp[((size_t)split * 2 + wc) * NROWS + q0 + wr*32 + rt*16 + g*4 + r] = d;
    }
}

// ---------------- kernel 3: combine partials, diagonal fix, output ----------------
__global__ __launch_bounds__(256) void combine_kernel(
    const float* __restrict__ x, const unsigned short* __restrict__ qb,
    const unsigned short* __restrict__ kb, const unsigned short* __restrict__ vb,
    const float* __restrict__ nump, const float* __restrict__ denp,
    float* __restrict__ out)
{
  const int t = threadIdx.x;
  const int w = t >> 6, l = t & 63;
  const int i = blockIdx.x * 4 + w;

  ushort4 q4 = *(const ushort4*)(qb + (size_t)i * DDIM + l * 4);
  ushort4 k4 = *(const ushort4*)(kb + (size_t)i * DDIM + l * 4);
  float s = bf2f(q4.x) * bf2f(k4.x) + bf2f(q4.y) * bf2f(k4.y)
          + bf2f(q4.z) * bf2f(k4.z) + bf2f(q4.w) * bf2f(k4.w);
  #pragma unroll
  for (int m = 1; m < 64; m <<= 1) s += __shfl_xor(s, m);
  float r  = fmaxf(s, 0.f);
  float rb = bf2f(f2bf_bits(r));   // match attn's bf16-rounded P value

  float den = 0.f;
  #pragma unroll
  for (int sp = 0; sp < KSPLIT; sp++)
    den += denp[(size_t)(sp * 2) * NROWS + i] + denp[(size_t)(sp * 2 + 1) * NROWS + i];
  float inv = 1.f / fmaxf(den - r, 1e-12f);

  const int d0 = l * 4;
  float4 acc = *(const float4*)(nump + (size_t)i * DDIM + d0);
  #pragma unroll
  for (int sp = 1; sp < KSPLIT; sp++) {
    float4 a2 = *(const float4*)(nump + (size_t)sp * NROWS * DDIM + (size_t)i * DDIM + d0);
    acc.x += a2.x; acc.y += a2.y; acc.z += a2.z; acc.w += a2.w;
  }
  ushort4 v4 = *(const ushort4*)(vb + (size_t)i * DDIM + d0);
  float4 xx = *(const float4*)(x + (size_t)i * DDIM + d0);
  float4 o;
  o.x = (acc.x - rb * bf2f(v4.x)) * inv + xx.x;
  o.y = (acc.y - rb * bf2f(v4.y)) * inv + xx.y;
  o.z = (acc.z - rb * bf2f(v4.z)) * inv + xx.z;
  o.w = (acc.w - rb * bf2f(v4.w)) * inv + xx.w;
  *(float4*)(out + (size_t)i * DDIM + d0) = o;
}

extern "C" void kernel_launch(void* const* d_in, const int* in_sizes, int n_in,
                              void* d_out, int out_size, void* d_ws, size_t ws_size,
                              hipStream_t stream)
{
  const float* x  = (const float*)d_in[0];
  const float* Wq = (const float*)d_in[1];
  const float* bq = (const float*)d_in[2];
  const float* Wk = (const float*)d_in[3];
  const float* bk = (const float*)d_in[4];
  const float* Wv = (const float*)d_in[5];
  const float* bv = (const float*)d_in[6];

  char* ws = (char*)d_ws;
  unsigned short* xb  = (unsigned short*)(ws + 0);          // 4 MB
  unsigned short* Wb  = (unsigned short*)(ws + 4194304);    // 384 KB (3 matrices)
  unsigned short* qb  = (unsigned short*)(ws + 4587520);    // 4 MB
  unsigned short* kb  = (unsigned short*)(ws + 8781824);    // 4 MB
  unsigned short* vb  = (unsigned short*)(ws + 12976128);   // 4 MB
  unsigned short* vT  = (unsigned short*)(ws + 17170432);   // 4 MB
  float* nump = (float*)(ws + 21364736);                    // 32 MB (4 splits)
  float* denp = (float*)(ws + 54919168);                    // 256 KB

  convert_kernel<<<2240, 256, 0, stream>>>(x, Wq, Wk, Wv, xb, Wb);
  qkv_kernel<<<384, 256, 0, stream>>>(bq, bk, bv, xb, Wb, qb, kb, vb, vT);
  attn_kernel<<<(NROWS / BM) * KSPLIT, 512, 0, stream>>>(qb, kb, vT, nump, denp);
  combine_kernel<<<NROWS / 4, 256, 0, stream>>>(x, qb, kb, vb, nump, denp, (float*)d_out);
}